// Round 6
// baseline (1021.272 us; speedup 1.0000x reference)
//
#include <hip/hip_runtime.h>

typedef __bf16 bf16x8 __attribute__((ext_vector_type(8)));
typedef __bf16 bf16x2 __attribute__((ext_vector_type(2)));
typedef float f32x4 __attribute__((ext_vector_type(4)));

#define N_NODES 50000
#define N_EDGES 800000
#define MAXDEG 128
#define BA_OFF 0
#define BV_OFF (N_NODES * 64)

// ---- workspace layout (byte offsets)
#define REC_OFF   0ull            // 50000*128 bf16 = 12.8 MB node records
#define CNT_OFF   12800000ull     // 50000 int degree counts
#define ELL_OFF   13000192ull     // 50000*128 int edge ids = 25.6 MB

// ---- LDS weight layout (ushort units). K=64 rows padded to 72, K=32 rows to 40
#define OFF_WFOLD 0              // 32 x 40
#define OFF_WCAT  1280           // 64 x 72  [WY000 | WY110]
#define OFF_W011  5888           // 16 x 40
#define OFF_WV    6528           // 16 x 72  [WY101 | WY111]
#define OFF_WM1   7680           // 64 x 72
#define OFF_WM2   12288
#define OFF_WM3   16896
#define W_USHORTS 21504

#if defined(__has_builtin)
#if __has_builtin(__builtin_amdgcn_cvt_pk_bf16_f32)
#define HAVE_PK_BF16 1
#endif
#endif

__device__ __forceinline__ unsigned short f2bf(float x) {
    unsigned u = __float_as_uint(x);
    return (unsigned short)((u + 0x7FFFu + ((u >> 16) & 1u)) >> 16);
}
__device__ __forceinline__ unsigned pack2(float a, float b) {
#ifdef HAVE_PK_BF16
    union { bf16x2 h; unsigned u; } cv;
    cv.h = __builtin_amdgcn_cvt_pk_bf16_f32(a, b);
    return cv.u;
#else
    return (unsigned)f2bf(a) | ((unsigned)f2bf(b) << 16);
#endif
}
__device__ __forceinline__ float bf2f(unsigned short h) {
    return __uint_as_float(((unsigned)h) << 16);
}

// ---------------- node features: La = x_a @ W_L0.T ; Lv = einsum(ndi,cd->nci)
// record per node (bf16): [La(32) | Lvx(32) | Lvy(32) | Lvz(32)]
__global__ __launch_bounds__(256) void node_kernel(
    const float* __restrict__ x_a, const float* __restrict__ x_v,
    const float* __restrict__ W_L0, const float* __restrict__ W_L1,
    unsigned short* __restrict__ rec)
{
    int t = blockIdx.x * 256 + threadIdx.x;
    if (t >= N_NODES * 32) return;
    int n = t >> 5, c = t & 31;
    const float* xa = x_a + (size_t)n * 64;
    const float* w0 = W_L0 + c * 64;
    float accA = 0.f;
#pragma unroll
    for (int k = 0; k < 64; ++k) accA += xa[k] * w0[k];
    const float* xv = x_v + (size_t)n * 48;
    const float* w1 = W_L1 + c * 16;
    float a0 = 0.f, a1 = 0.f, a2 = 0.f;
#pragma unroll
    for (int d = 0; d < 16; ++d) {
        float w = w1[d];
        a0 += xv[d * 3 + 0] * w;
        a1 += xv[d * 3 + 1] * w;
        a2 += xv[d * 3 + 2] * w;
    }
    unsigned short* rp = rec + (size_t)n * 128;
    rp[c]      = f2bf(accA);
    rp[32 + c] = f2bf(a0);
    rp[64 + c] = f2bf(a1);
    rp[96 + c] = f2bf(a2);
}

// ---------------- ELL build: bump-allocate each edge into its src node's list
__global__ __launch_bounds__(256) void ell_kernel(
    const int* __restrict__ src, int* __restrict__ cnt, int* __restrict__ ell)
{
    int e = blockIdx.x * 256 + threadIdx.x;
    if (e >= N_EDGES) return;
    int s = src[e];
    int o = atomicAdd(&cnt[s], 1);
    if (o < MAXDEG) ell[(size_t)s * MAXDEG + o] = e;
}

// ---------------- node-major fused kernel: one wave = one node, 16 edges/tile
__global__ __launch_bounds__(256, 3) void node_major_kernel(
    const float* __restrict__ r_ij, const int* __restrict__ dst,
    const float* __restrict__ W_enc, const float* __restrict__ b_enc,
    const float* __restrict__ WY000, const float* __restrict__ WY110,
    const float* __restrict__ WY011, const float* __restrict__ WY101, const float* __restrict__ WY111,
    const float* __restrict__ Wm1, const float* __restrict__ bm1,
    const float* __restrict__ Wm2, const float* __restrict__ bm2,
    const float* __restrict__ Wm3,
    const unsigned short* __restrict__ rec,
    const int* __restrict__ cnt, const int* __restrict__ ell,
    float* __restrict__ out)
{
    __shared__ __align__(16) unsigned short Wlds[W_USHORTS];
    __shared__ __align__(16) unsigned short Buf[4][1152];   // one 16x72 buffer per wave, reused
    __shared__ __align__(16) float Bias[160];   // b_enc[0:32], b_m1[32:96], b_m2[96:160]

    const int tid = threadIdx.x;

    // ---- stage weights to LDS (bf16), fold W_enc over duplicated coeffs
    for (int idx = tid; idx < 1024; idx += 256) {
        int c = idx >> 5, k = idx & 31;
        float v;
        if (k < 16) v = W_enc[c * 64 + 2 * k] + W_enc[c * 64 + 2 * k + 1];
        else        v = W_enc[c * 64 + 32 + 2 * (k - 16)] + W_enc[c * 64 + 32 + 2 * (k - 16) + 1];
        Wlds[OFF_WFOLD + c * 40 + k] = f2bf(v);
    }
    for (int idx = tid; idx < 4096; idx += 256) {
        int d = idx >> 6, k = idx & 63;
        float v = (k < 32) ? WY000[d * 32 + k] : WY110[d * 32 + (k - 32)];
        Wlds[OFF_WCAT + d * 72 + k] = f2bf(v);
        Wlds[OFF_WM1 + d * 72 + k] = f2bf(Wm1[d * 64 + k]);
        Wlds[OFF_WM2 + d * 72 + k] = f2bf(Wm2[d * 64 + k]);
        Wlds[OFF_WM3 + d * 72 + k] = f2bf(Wm3[d * 64 + k]);
    }
    for (int idx = tid; idx < 512; idx += 256) {
        int vv = idx >> 5, k = idx & 31;
        Wlds[OFF_W011 + vv * 40 + k] = f2bf(WY011[vv * 32 + k]);
    }
    for (int idx = tid; idx < 1024; idx += 256) {
        int vv = idx >> 6, k = idx & 63;
        float w = (k < 32) ? WY101[vv * 32 + k] : WY111[vv * 32 + (k - 32)];
        Wlds[OFF_WV + vv * 72 + k] = f2bf(w);
    }
    if (tid < 32) Bias[tid] = b_enc[tid];
    if (tid < 64) { Bias[32 + tid] = bm1[tid]; Bias[96 + tid] = bm2[tid]; }
    __syncthreads();

    const int wid  = tid >> 6;
    const int lane = tid & 63;
    const int col  = lane & 15;   // edge-slot-in-tile (MFMA n / A-row m)
    const int quad = lane >> 4;   // K-group / C-row group

    unsigned short* buf = &Buf[wid][0];   // reused: ya -> yv -> hb (in-order DS pipe, wave-private)

    const f32x4 zero = {0.f, 0.f, 0.f, 0.f};
    float* __restrict__ outA = out + BA_OFF;
    float* __restrict__ outV = out + BV_OFF;

    for (int n = blockIdx.x * 4 + wid; n < N_NODES; n += gridDim.x * 4) {
        int deg = cnt[n];
        deg = (deg < MAXDEG) ? deg : MAXDEG;
        const int* el = ell + (size_t)n * MAXDEG;

        float accA[4][4];
        float accV[12];
#pragma unroll
        for (int mt = 0; mt < 4; ++mt)
#pragma unroll
            for (int r = 0; r < 4; ++r) accA[mt][r] = 0.f;
#pragma unroll
        for (int j = 0; j < 12; ++j) accV[j] = 0.f;

        if (deg > 0) {
            // head of tile 0's dependent chain (id -> dst/r)
            int jc = (col < deg) ? col : (deg - 1);
            int eid0 = el[jc];
            int nd = dst[eid0];
            float r0 = r_ij[eid0 * 3 + 0], r1 = r_ij[eid0 * 3 + 1], r2 = r_ij[eid0 * 3 + 2];

            for (int j0 = 0; j0 < deg; j0 += 16) {
                // ---- rec gather: addresses ready at loop top (nd prefetched last iter)
                const unsigned short* rp = rec + (size_t)nd * 128;
                ushort4 qa0 = *(const ushort4*)&rp[quad * 4];
                ushort4 qa1 = *(const ushort4*)&rp[16 + quad * 4];
                ushort4 qv[6];
#pragma unroll
                for (int i = 0; i < 3; ++i)
#pragma unroll
                    for (int mt = 0; mt < 2; ++mt)
                        qv[i * 2 + mt] = *(const ushort4*)&rp[32 + i * 32 + mt * 16 + quad * 4];

                // ---- 4-register prefetch of the NEXT tile's chain head (hides el->dst->r_ij)
                int jn = j0 + 16 + col;
                jn = (jn < deg) ? jn : (deg - 1);
                int eidn = el[jn];
                int ndn = dst[eidn];
                float nr0 = r_ij[eidn * 3 + 0], nr1 = r_ij[eidn * 3 + 1], nr2 = r_ij[eidn * 3 + 2];

                const float validf = (j0 + col < deg) ? 1.f : 0.f;

                // ---- per-edge geometry (r already in registers)
                float u  = sqrtf(r0 * r0 + r1 * r1 + r2 * r2);
                float a  = 0.6283185307f * u;          // (pi/5) * dist
                float s14 = 1.4f * u;
                float th  = tanhf(s14);
                float f   = th / fmaxf(s14, 1e-12f);
                float rh0 = 1.4f * r0 * f, rh1 = 1.4f * r1 * f, rh2 = 1.4f * r2 * f;

                // ---- radial features: quads 0/1 cos((k+1)a), quads 2/3 sin; odd quads start at k=8
                float c1 = cosf(a), s1 = sinf(a);
                float c2 = c1 * c1 - s1 * s1, s2 = 2.f * c1 * s1;
                float c4 = c2 * c2 - s2 * s2, s4 = 2.f * c2 * s2;
                float c8 = c4 * c4 - s4 * s4, s8 = 2.f * c4 * s4;
                float cc, ss;
                if (quad & 1) { cc = c8 * c1 - s8 * s1; ss = s8 * c1 + c8 * s1; }
                else          { cc = c1; ss = s1; }
                float rvf[8];
                bool usec = (quad < 2);
#pragma unroll
                for (int jj = 0; jj < 8; ++jj) {
                    rvf[jj] = usec ? cc : ss;
                    float cn = cc * c1 - ss * s1; ss = ss * c1 + cc * s1; cc = cn;
                }
                union { unsigned u4[4]; bf16x8 v; } brU;
                brU.u4[0] = pack2(rvf[0], rvf[1]);
                brU.u4[1] = pack2(rvf[2], rvf[3]);
                brU.u4[2] = pack2(rvf[4], rvf[5]);
                brU.u4[3] = pack2(rvf[6], rvf[7]);
                bf16x8 brad = brU.v;   // lane already holds its own B-fragment — no LDS trip

                // ---- phi GEMM: phi(32 x 16e) = Wfold(32x32) @ rad(32 x 16e)
                float phi[2][4];
#pragma unroll
                for (int mt = 0; mt < 2; ++mt) {
                    bf16x8 aw = *(const bf16x8*)&Wlds[OFF_WFOLD + (mt * 16 + col) * 40 + quad * 8];
                    f32x4 pa = __builtin_amdgcn_mfma_f32_16x16x32_bf16(aw, brad, zero, 0, 0, 0);
#pragma unroll
                    for (int r = 0; r < 4; ++r)
                        phi[mt][r] = (pa[r] + Bias[mt * 16 + quad * 4 + r]) * validf;
                }

                // ---- unpack node features (loads issued at loop top)
                float la[2][4], lv[3][2][4];
                {
                    la[0][0] = bf2f(qa0.x); la[0][1] = bf2f(qa0.y); la[0][2] = bf2f(qa0.z); la[0][3] = bf2f(qa0.w);
                    la[1][0] = bf2f(qa1.x); la[1][1] = bf2f(qa1.y); la[1][2] = bf2f(qa1.z); la[1][3] = bf2f(qa1.w);
#pragma unroll
                    for (int i = 0; i < 3; ++i)
#pragma unroll
                        for (int mt = 0; mt < 2; ++mt) {
                            ushort4 p = qv[i * 2 + mt];
                            lv[i][mt][0] = bf2f(p.x); lv[i][mt][1] = bf2f(p.y);
                            lv[i][mt][2] = bf2f(p.z); lv[i][mt][3] = bf2f(p.w);
                        }
                }

                // ---- order-0 tensor products -> buf = [y000 | y110] (16e x 64k)
#pragma unroll
                for (int mt = 0; mt < 2; ++mt) {
                    float y0[4], y1[4];
#pragma unroll
                    for (int r = 0; r < 4; ++r) {
                        float dotv = lv[0][mt][r] * rh0 + lv[1][mt][r] * rh1 + lv[2][mt][r] * rh2;
                        y0[r] = la[mt][r] * phi[mt][r];
                        y1[r] = phi[mt][r] * dotv;
                    }
                    uint2 w0; w0.x = pack2(y0[0], y0[1]); w0.y = pack2(y0[2], y0[3]);
                    *(uint2*)&buf[col * 72 + mt * 16 + quad * 4] = w0;
                    uint2 w1; w1.x = pack2(y1[0], y1[1]); w1.y = pack2(y1[2], y1[3]);
                    *(uint2*)&buf[col * 72 + 32 + mt * 16 + quad * 4] = w1;
                }

                // ---- psi_a = [y000|y110] @ [WY000|WY110].T   (64 out)
                f32x4 pacc[4] = {zero, zero, zero, zero};
#pragma unroll
                for (int ks = 0; ks < 2; ++ks) {
                    bf16x8 bb = *(const bf16x8*)&buf[col * 72 + ks * 32 + quad * 8];
#pragma unroll
                    for (int mt = 0; mt < 4; ++mt) {
                        bf16x8 aa = *(const bf16x8*)&Wlds[OFF_WCAT + (mt * 16 + col) * 72 + ks * 32 + quad * 8];
                        pacc[mt] = __builtin_amdgcn_mfma_f32_16x16x32_bf16(aa, bb, pacc[mt], 0, 0, 0);
                    }
                }
                // ---- fold residual NOW (kills the psi fp32 live range) and keep only
                //      the bf16-packed MLP input (8 regs instead of 16)
                uint2 psiPk[4];
#pragma unroll
                for (int mt = 0; mt < 4; ++mt) {
#pragma unroll
                    for (int r = 0; r < 4; ++r)
                        accA[mt][r] = fmaf(0.1f * pacc[mt][r], validf, accA[mt][r]);
                    psiPk[mt].x = pack2(pacc[mt][0], pacc[mt][1]);
                    psiPk[mt].y = pack2(pacc[mt][2], pacc[mt][3]);
                }

                // ---- t011 = y000 @ WY011.T (16 out, K=32)  [buf still holds ya]
                bf16x8 b0 = *(const bf16x8*)&buf[col * 72 + quad * 8];
                bf16x8 a011 = *(const bf16x8*)&Wlds[OFF_W011 + col * 40 + quad * 8];
                f32x4 t011v = __builtin_amdgcn_mfma_f32_16x16x32_bf16(a011, b0, zero, 0, 0, 0);

                // ---- psi_v per component: [y101_i|y111_i] @ [WY101|WY111].T + t011*rh_i
                // phi==0 for invalid lanes => all products zero => no masking needed on accV
#pragma unroll
                for (int i = 0; i < 3; ++i) {
#pragma unroll
                    for (int mt = 0; mt < 2; ++mt) {
                        float q1[4], q2[4];
#pragma unroll
                        for (int r = 0; r < 4; ++r) {
                            q1[r] = phi[mt][r] * lv[i][mt][r];
                            float cr;
                            if (i == 0)      cr = lv[1][mt][r] * rh2 - lv[2][mt][r] * rh1;
                            else if (i == 1) cr = lv[2][mt][r] * rh0 - lv[0][mt][r] * rh2;
                            else             cr = lv[0][mt][r] * rh1 - lv[1][mt][r] * rh0;
                            q2[r] = phi[mt][r] * cr;
                        }
                        uint2 wa; wa.x = pack2(q1[0], q1[1]); wa.y = pack2(q1[2], q1[3]);
                        *(uint2*)&buf[col * 72 + mt * 16 + quad * 4] = wa;
                        uint2 wb; wb.x = pack2(q2[0], q2[1]); wb.y = pack2(q2[2], q2[3]);
                        *(uint2*)&buf[col * 72 + 32 + mt * 16 + quad * 4] = wb;
                    }
                    f32x4 vacc = zero;
#pragma unroll
                    for (int ks = 0; ks < 2; ++ks) {
                        bf16x8 bb = *(const bf16x8*)&buf[col * 72 + ks * 32 + quad * 8];
                        bf16x8 aa = *(const bf16x8*)&Wlds[OFF_WV + col * 72 + ks * 32 + quad * 8];
                        vacc = __builtin_amdgcn_mfma_f32_16x16x32_bf16(aa, bb, vacc, 0, 0, 0);
                    }
                    float rhi = (i == 0) ? rh0 : (i == 1) ? rh1 : rh2;
#pragma unroll
                    for (int r = 0; r < 4; ++r)
                        accV[r * 3 + i] += 0.1f * (vacc[r] + t011v[r] * rhi);
                }

                // ---- residual MLP on psi_a (3x 64x64 GEMM, leaky_relu 0.1)
#pragma unroll
                for (int mt = 0; mt < 4; ++mt)
                    *(uint2*)&buf[col * 72 + mt * 16 + quad * 4] = psiPk[mt];
                // layer 1
                f32x4 hacc[4] = {zero, zero, zero, zero};
#pragma unroll
                for (int ks = 0; ks < 2; ++ks) {
                    bf16x8 bb = *(const bf16x8*)&buf[col * 72 + ks * 32 + quad * 8];
#pragma unroll
                    for (int mt = 0; mt < 4; ++mt) {
                        bf16x8 aa = *(const bf16x8*)&Wlds[OFF_WM1 + (mt * 16 + col) * 72 + ks * 32 + quad * 8];
                        hacc[mt] = __builtin_amdgcn_mfma_f32_16x16x32_bf16(aa, bb, hacc[mt], 0, 0, 0);
                    }
                }
#pragma unroll
                for (int mt = 0; mt < 4; ++mt) {
                    float h[4];
#pragma unroll
                    for (int r = 0; r < 4; ++r) {
                        float x = hacc[mt][r] + Bias[32 + mt * 16 + quad * 4 + r];
                        h[r] = fmaxf(x, 0.1f * x);
                    }
                    uint2 w; w.x = pack2(h[0], h[1]); w.y = pack2(h[2], h[3]);
                    *(uint2*)&buf[col * 72 + mt * 16 + quad * 4] = w;
                }
                // layer 2
                f32x4 gacc[4] = {zero, zero, zero, zero};
#pragma unroll
                for (int ks = 0; ks < 2; ++ks) {
                    bf16x8 bb = *(const bf16x8*)&buf[col * 72 + ks * 32 + quad * 8];
#pragma unroll
                    for (int mt = 0; mt < 4; ++mt) {
                        bf16x8 aa = *(const bf16x8*)&Wlds[OFF_WM2 + (mt * 16 + col) * 72 + ks * 32 + quad * 8];
                        gacc[mt] = __builtin_amdgcn_mfma_f32_16x16x32_bf16(aa, bb, gacc[mt], 0, 0, 0);
                    }
                }
#pragma unroll
                for (int mt = 0; mt < 4; ++mt) {
                    float h[4];
#pragma unroll
                    for (int r = 0; r < 4; ++r) {
                        float x = gacc[mt][r] + Bias[96 + mt * 16 + quad * 4 + r];
                        h[r] = fmaxf(x, 0.1f * x);
                    }
                    uint2 w; w.x = pack2(h[0], h[1]); w.y = pack2(h[2], h[3]);
                    *(uint2*)&buf[col * 72 + mt * 16 + quad * 4] = w;
                }
                // layer 3 (no bias) + scale + accumulate (masked via validf; psi already folded)
                f32x4 oacc[4] = {zero, zero, zero, zero};
#pragma unroll
                for (int ks = 0; ks < 2; ++ks) {
                    bf16x8 bb = *(const bf16x8*)&buf[col * 72 + ks * 32 + quad * 8];
#pragma unroll
                    for (int mt = 0; mt < 4; ++mt) {
                        bf16x8 aa = *(const bf16x8*)&Wlds[OFF_WM3 + (mt * 16 + col) * 72 + ks * 32 + quad * 8];
                        oacc[mt] = __builtin_amdgcn_mfma_f32_16x16x32_bf16(aa, bb, oacc[mt], 0, 0, 0);
                    }
                }
#pragma unroll
                for (int mt = 0; mt < 4; ++mt)
#pragma unroll
                    for (int r = 0; r < 4; ++r)
                        accA[mt][r] = fmaf(0.1f * oacc[mt][r], validf, accA[mt][r]);

                nd = ndn; r0 = nr0; r1 = nr1; r2 = nr2;
            }
        }

        // ---- butterfly reduction across the 16 cols (lanes quad*16 + col)
#pragma unroll
        for (int d2 = 1; d2 < 16; d2 <<= 1) {
#pragma unroll
            for (int mt = 0; mt < 4; ++mt)
#pragma unroll
                for (int r = 0; r < 4; ++r) accA[mt][r] += __shfl_xor(accA[mt][r], d2);
#pragma unroll
            for (int j = 0; j < 12; ++j) accV[j] += __shfl_xor(accV[j], d2);
        }

        // ---- store (col 0 lanes: one per quad)
        if (col == 0) {
#pragma unroll
            for (int mt = 0; mt < 4; ++mt) {
                float4 st = {accA[mt][0], accA[mt][1], accA[mt][2], accA[mt][3]};
                *(float4*)&outA[(size_t)n * 64 + mt * 16 + quad * 4] = st;
            }
#pragma unroll
            for (int j = 0; j < 3; ++j) {
                float4 st = {accV[j * 4 + 0], accV[j * 4 + 1], accV[j * 4 + 2], accV[j * 4 + 3]};
                *(float4*)&outV[(size_t)n * 48 + quad * 12 + j * 4] = st;
            }
        }
    }
}

extern "C" void kernel_launch(void* const* d_in, const int* in_sizes, int n_in,
                              void* d_out, int out_size, void* d_ws, size_t ws_size,
                              hipStream_t stream) {
    const float* r_ij  = (const float*)d_in[0];
    const float* x_a   = (const float*)d_in[1];
    const float* x_v   = (const float*)d_in[2];
    const int*   src   = (const int*)d_in[3];
    const int*   dst   = (const int*)d_in[4];
    const float* W_L0  = (const float*)d_in[5];
    const float* W_L1  = (const float*)d_in[6];
    const float* W_enc = (const float*)d_in[7];
    const float* b_enc = (const float*)d_in[8];
    const float* WY000 = (const float*)d_in[9];
    const float* WY110 = (const float*)d_in[10];
    const float* WY011 = (const float*)d_in[11];
    const float* WY101 = (const float*)d_in[12];
    const float* WY111 = (const float*)d_in[13];
    const float* Wm1   = (const float*)d_in[14];
    const float* bm1   = (const float*)d_in[15];
    const float* Wm2   = (const float*)d_in[16];
    const float* bm2   = (const float*)d_in[17];
    const float* Wm3   = (const float*)d_in[18];
    float* out = (float*)d_out;

    char* ws = (char*)d_ws;
    unsigned short* rec = (unsigned short*)(ws + REC_OFF);
    int* cnt            = (int*)(ws + CNT_OFF);
    int* ell            = (int*)(ws + ELL_OFF);

    hipMemsetAsync(d_out, 0, (size_t)out_size * sizeof(float), stream);
    hipMemsetAsync(cnt, 0, N_NODES * sizeof(int), stream);

    node_kernel<<<(N_NODES * 32) / 256, 256, 0, stream>>>(x_a, x_v, W_L0, W_L1, rec);
    ell_kernel<<<(N_EDGES + 255) / 256, 256, 0, stream>>>(src, cnt, ell);
    node_major_kernel<<<2048, 256, 0, stream>>>(r_ij, dst, W_enc, b_enc,
            WY000, WY110, WY011, WY101, WY111, Wm1, bm1, Wm2, bm2, Wm3,
            rec, cnt, ell, out);
}

// Round 7
// 590.463 us; speedup vs baseline: 1.7296x; 1.7296x over previous
//
#include <hip/hip_runtime.h>

typedef __bf16 bf16x8 __attribute__((ext_vector_type(8)));
typedef __bf16 bf16x2 __attribute__((ext_vector_type(2)));
typedef float f32x4 __attribute__((ext_vector_type(4)));

#define N_NODES 50000
#define N_EDGES 800000
#define MAXDEG 128
#define BA_OFF 0
#define BV_OFF (N_NODES * 64)

// ---- workspace layout (byte offsets)
#define REC_OFF   0ull            // 50000*128 bf16 = 12.8 MB node records
#define CNT_OFF   12800000ull     // 50000 int degree counts
#define ELL_OFF   13000192ull     // 50000*128 int edge ids = 25.6 MB

// ---- LDS weight layout (ushort units). K=64 rows padded to 72, K=32 rows to 40
#define OFF_WFOLD 0              // 32 x 40
#define OFF_WCAT  1280           // 64 x 72  [WY000 | WY110]
#define OFF_W011  5888           // 16 x 40
#define OFF_WV    6528           // 16 x 72  [WY101 | WY111]
#define OFF_WM1   7680           // 64 x 72
#define OFF_WM2   12288
#define OFF_WM3   16896
#define W_USHORTS 21504

#if defined(__has_builtin)
#if __has_builtin(__builtin_amdgcn_cvt_pk_bf16_f32)
#define HAVE_PK_BF16 1
#endif
#endif

__device__ __forceinline__ unsigned short f2bf(float x) {
    unsigned u = __float_as_uint(x);
    return (unsigned short)((u + 0x7FFFu + ((u >> 16) & 1u)) >> 16);
}
__device__ __forceinline__ unsigned pack2(float a, float b) {
#ifdef HAVE_PK_BF16
    union { bf16x2 h; unsigned u; } cv;
    cv.h = __builtin_amdgcn_cvt_pk_bf16_f32(a, b);
    return cv.u;
#else
    return (unsigned)f2bf(a) | ((unsigned)f2bf(b) << 16);
#endif
}
__device__ __forceinline__ float bf2f(unsigned short h) {
    return __uint_as_float(((unsigned)h) << 16);
}

// ---------------- node features: La = x_a @ W_L0.T ; Lv = einsum(ndi,cd->nci)
// record per node (bf16): [La(32) | Lvx(32) | Lvy(32) | Lvz(32)]
__global__ __launch_bounds__(256) void node_kernel(
    const float* __restrict__ x_a, const float* __restrict__ x_v,
    const float* __restrict__ W_L0, const float* __restrict__ W_L1,
    unsigned short* __restrict__ rec)
{
    int t = blockIdx.x * 256 + threadIdx.x;
    if (t >= N_NODES * 32) return;
    int n = t >> 5, c = t & 31;
    const float* xa = x_a + (size_t)n * 64;
    const float* w0 = W_L0 + c * 64;
    float accA = 0.f;
#pragma unroll
    for (int k = 0; k < 64; ++k) accA += xa[k] * w0[k];
    const float* xv = x_v + (size_t)n * 48;
    const float* w1 = W_L1 + c * 16;
    float a0 = 0.f, a1 = 0.f, a2 = 0.f;
#pragma unroll
    for (int d = 0; d < 16; ++d) {
        float w = w1[d];
        a0 += xv[d * 3 + 0] * w;
        a1 += xv[d * 3 + 1] * w;
        a2 += xv[d * 3 + 2] * w;
    }
    unsigned short* rp = rec + (size_t)n * 128;
    rp[c]      = f2bf(accA);
    rp[32 + c] = f2bf(a0);
    rp[64 + c] = f2bf(a1);
    rp[96 + c] = f2bf(a2);
}

// ---------------- ELL build: bump-allocate each edge into its src node's list
__global__ __launch_bounds__(256) void ell_kernel(
    const int* __restrict__ src, int* __restrict__ cnt, int* __restrict__ ell)
{
    int e = blockIdx.x * 256 + threadIdx.x;
    if (e >= N_EDGES) return;
    int s = src[e];
    int o = atomicAdd(&cnt[s], 1);
    if (o < MAXDEG) ell[(size_t)s * MAXDEG + o] = e;
}

// ---------------- node-major fused kernel: one wave = one node, 16 edges/tile
// __launch_bounds__(256,1): VGPR cap 512 — the loop needs ~160 live regs; any
// lower cap (84 @ min3, 128 @ min2) caused 0.6-3.3 GB of scratch spill traffic.
__global__ __launch_bounds__(256, 1) void node_major_kernel(
    const float* __restrict__ r_ij, const int* __restrict__ dst,
    const float* __restrict__ W_enc, const float* __restrict__ b_enc,
    const float* __restrict__ WY000, const float* __restrict__ WY110,
    const float* __restrict__ WY011, const float* __restrict__ WY101, const float* __restrict__ WY111,
    const float* __restrict__ Wm1, const float* __restrict__ bm1,
    const float* __restrict__ Wm2, const float* __restrict__ bm2,
    const float* __restrict__ Wm3,
    const unsigned short* __restrict__ rec,
    const int* __restrict__ cnt, const int* __restrict__ ell,
    float* __restrict__ out)
{
    __shared__ __align__(16) unsigned short Wlds[W_USHORTS];
    __shared__ __align__(16) unsigned short Buf[4][1152];   // one 16x72 buffer per wave, reused
    __shared__ __align__(16) float Bias[160];   // b_enc[0:32], b_m1[32:96], b_m2[96:160]

    const int tid = threadIdx.x;

    // ---- stage weights to LDS (bf16), fold W_enc over duplicated coeffs
    for (int idx = tid; idx < 1024; idx += 256) {
        int c = idx >> 5, k = idx & 31;
        float v;
        if (k < 16) v = W_enc[c * 64 + 2 * k] + W_enc[c * 64 + 2 * k + 1];
        else        v = W_enc[c * 64 + 32 + 2 * (k - 16)] + W_enc[c * 64 + 32 + 2 * (k - 16) + 1];
        Wlds[OFF_WFOLD + c * 40 + k] = f2bf(v);
    }
    for (int idx = tid; idx < 4096; idx += 256) {
        int d = idx >> 6, k = idx & 63;
        float v = (k < 32) ? WY000[d * 32 + k] : WY110[d * 32 + (k - 32)];
        Wlds[OFF_WCAT + d * 72 + k] = f2bf(v);
        Wlds[OFF_WM1 + d * 72 + k] = f2bf(Wm1[d * 64 + k]);
        Wlds[OFF_WM2 + d * 72 + k] = f2bf(Wm2[d * 64 + k]);
        Wlds[OFF_WM3 + d * 72 + k] = f2bf(Wm3[d * 64 + k]);
    }
    for (int idx = tid; idx < 512; idx += 256) {
        int vv = idx >> 5, k = idx & 31;
        Wlds[OFF_W011 + vv * 40 + k] = f2bf(WY011[vv * 32 + k]);
    }
    for (int idx = tid; idx < 1024; idx += 256) {
        int vv = idx >> 6, k = idx & 63;
        float w = (k < 32) ? WY101[vv * 32 + k] : WY111[vv * 32 + (k - 32)];
        Wlds[OFF_WV + vv * 72 + k] = f2bf(w);
    }
    if (tid < 32) Bias[tid] = b_enc[tid];
    if (tid < 64) { Bias[32 + tid] = bm1[tid]; Bias[96 + tid] = bm2[tid]; }
    __syncthreads();

    const int wid  = tid >> 6;
    const int lane = tid & 63;
    const int col  = lane & 15;   // edge-slot-in-tile (MFMA n / A-row m)
    const int quad = lane >> 4;   // K-group / C-row group

    unsigned short* buf = &Buf[wid][0];   // reused: ya -> yv -> hb (in-order DS pipe, wave-private)

    const f32x4 zero = {0.f, 0.f, 0.f, 0.f};
    float* __restrict__ outA = out + BA_OFF;
    float* __restrict__ outV = out + BV_OFF;

    for (int n = blockIdx.x * 4 + wid; n < N_NODES; n += gridDim.x * 4) {
        int deg = cnt[n];
        deg = (deg < MAXDEG) ? deg : MAXDEG;
        const int* el = ell + (size_t)n * MAXDEG;

        float accA[4][4];
        float accV[12];
#pragma unroll
        for (int mt = 0; mt < 4; ++mt)
#pragma unroll
            for (int r = 0; r < 4; ++r) accA[mt][r] = 0.f;
#pragma unroll
        for (int j = 0; j < 12; ++j) accV[j] = 0.f;

        if (deg > 0) {
            // head of tile 0's dependent chain (id -> dst/r)
            int jc = (col < deg) ? col : (deg - 1);
            int eid0 = el[jc];
            int nd = dst[eid0];
            float r0 = r_ij[eid0 * 3 + 0], r1 = r_ij[eid0 * 3 + 1], r2 = r_ij[eid0 * 3 + 2];

            for (int j0 = 0; j0 < deg; j0 += 16) {
                // ---- rec gather: addresses ready at loop top (nd prefetched last iter)
                const unsigned short* rp = rec + (size_t)nd * 128;
                ushort4 qa0 = *(const ushort4*)&rp[quad * 4];
                ushort4 qa1 = *(const ushort4*)&rp[16 + quad * 4];
                ushort4 qv[6];
#pragma unroll
                for (int i = 0; i < 3; ++i)
#pragma unroll
                    for (int mt = 0; mt < 2; ++mt)
                        qv[i * 2 + mt] = *(const ushort4*)&rp[32 + i * 32 + mt * 16 + quad * 4];

                // ---- 4-register prefetch of the NEXT tile's chain head (hides el->dst->r_ij)
                int jn = j0 + 16 + col;
                jn = (jn < deg) ? jn : (deg - 1);
                int eidn = el[jn];
                int ndn = dst[eidn];
                float nr0 = r_ij[eidn * 3 + 0], nr1 = r_ij[eidn * 3 + 1], nr2 = r_ij[eidn * 3 + 2];

                const float validf = (j0 + col < deg) ? 1.f : 0.f;

                // ---- per-edge geometry (r already in registers)
                float u  = sqrtf(r0 * r0 + r1 * r1 + r2 * r2);
                float a  = 0.6283185307f * u;          // (pi/5) * dist
                float s14 = 1.4f * u;
                float th  = tanhf(s14);
                float f   = th / fmaxf(s14, 1e-12f);
                float rh0 = 1.4f * r0 * f, rh1 = 1.4f * r1 * f, rh2 = 1.4f * r2 * f;

                // ---- radial features: quads 0/1 cos((k+1)a), quads 2/3 sin; odd quads start at k=8
                float c1 = cosf(a), s1 = sinf(a);
                float c2 = c1 * c1 - s1 * s1, s2 = 2.f * c1 * s1;
                float c4 = c2 * c2 - s2 * s2, s4 = 2.f * c2 * s2;
                float c8 = c4 * c4 - s4 * s4, s8 = 2.f * c4 * s4;
                float cc, ss;
                if (quad & 1) { cc = c8 * c1 - s8 * s1; ss = s8 * c1 + c8 * s1; }
                else          { cc = c1; ss = s1; }
                float rvf[8];
                bool usec = (quad < 2);
#pragma unroll
                for (int jj = 0; jj < 8; ++jj) {
                    rvf[jj] = usec ? cc : ss;
                    float cn = cc * c1 - ss * s1; ss = ss * c1 + cc * s1; cc = cn;
                }
                union { unsigned u4[4]; bf16x8 v; } brU;
                brU.u4[0] = pack2(rvf[0], rvf[1]);
                brU.u4[1] = pack2(rvf[2], rvf[3]);
                brU.u4[2] = pack2(rvf[4], rvf[5]);
                brU.u4[3] = pack2(rvf[6], rvf[7]);
                bf16x8 brad = brU.v;   // lane already holds its own B-fragment — no LDS trip

                // ---- phi GEMM: phi(32 x 16e) = Wfold(32x32) @ rad(32 x 16e)
                float phi[2][4];
#pragma unroll
                for (int mt = 0; mt < 2; ++mt) {
                    bf16x8 aw = *(const bf16x8*)&Wlds[OFF_WFOLD + (mt * 16 + col) * 40 + quad * 8];
                    f32x4 pa = __builtin_amdgcn_mfma_f32_16x16x32_bf16(aw, brad, zero, 0, 0, 0);
#pragma unroll
                    for (int r = 0; r < 4; ++r)
                        phi[mt][r] = (pa[r] + Bias[mt * 16 + quad * 4 + r]) * validf;
                }

                // ---- unpack vector node features (loads issued at loop top)
                float lv[3][2][4];
#pragma unroll
                for (int i = 0; i < 3; ++i)
#pragma unroll
                    for (int mt = 0; mt < 2; ++mt) {
                        ushort4 p = qv[i * 2 + mt];
                        lv[i][mt][0] = bf2f(p.x); lv[i][mt][1] = bf2f(p.y);
                        lv[i][mt][2] = bf2f(p.z); lv[i][mt][3] = bf2f(p.w);
                    }

                // ---- order-0 tensor products -> buf = [y000 | y110] (16e x 64k)
                // (la unpacked here from qa at its single use — keeps it packed otherwise)
#pragma unroll
                for (int mt = 0; mt < 2; ++mt) {
                    const ushort4 qa = (mt == 0) ? qa0 : qa1;
                    float laf[4] = {bf2f(qa.x), bf2f(qa.y), bf2f(qa.z), bf2f(qa.w)};
                    float y0[4], y1[4];
#pragma unroll
                    for (int r = 0; r < 4; ++r) {
                        float dotv = lv[0][mt][r] * rh0 + lv[1][mt][r] * rh1 + lv[2][mt][r] * rh2;
                        y0[r] = laf[r] * phi[mt][r];
                        y1[r] = phi[mt][r] * dotv;
                    }
                    uint2 w0; w0.x = pack2(y0[0], y0[1]); w0.y = pack2(y0[2], y0[3]);
                    *(uint2*)&buf[col * 72 + mt * 16 + quad * 4] = w0;
                    uint2 w1; w1.x = pack2(y1[0], y1[1]); w1.y = pack2(y1[2], y1[3]);
                    *(uint2*)&buf[col * 72 + 32 + mt * 16 + quad * 4] = w1;
                }

                // ---- psi_a = [y000|y110] @ [WY000|WY110].T   (64 out)
                f32x4 pacc[4] = {zero, zero, zero, zero};
#pragma unroll
                for (int ks = 0; ks < 2; ++ks) {
                    bf16x8 bb = *(const bf16x8*)&buf[col * 72 + ks * 32 + quad * 8];
#pragma unroll
                    for (int mt = 0; mt < 4; ++mt) {
                        bf16x8 aa = *(const bf16x8*)&Wlds[OFF_WCAT + (mt * 16 + col) * 72 + ks * 32 + quad * 8];
                        pacc[mt] = __builtin_amdgcn_mfma_f32_16x16x32_bf16(aa, bb, pacc[mt], 0, 0, 0);
                    }
                }
                // ---- fold residual NOW (kills the psi fp32 live range) and keep only
                //      the bf16-packed MLP input (8 regs instead of 16)
                uint2 psiPk[4];
#pragma unroll
                for (int mt = 0; mt < 4; ++mt) {
#pragma unroll
                    for (int r = 0; r < 4; ++r)
                        accA[mt][r] = fmaf(0.1f * pacc[mt][r], validf, accA[mt][r]);
                    psiPk[mt].x = pack2(pacc[mt][0], pacc[mt][1]);
                    psiPk[mt].y = pack2(pacc[mt][2], pacc[mt][3]);
                }

                // ---- t011 = y000 @ WY011.T (16 out, K=32)  [buf still holds ya]
                bf16x8 b0 = *(const bf16x8*)&buf[col * 72 + quad * 8];
                bf16x8 a011 = *(const bf16x8*)&Wlds[OFF_W011 + col * 40 + quad * 8];
                f32x4 t011v = __builtin_amdgcn_mfma_f32_16x16x32_bf16(a011, b0, zero, 0, 0, 0);

                // ---- psi_v per component: [y101_i|y111_i] @ [WY101|WY111].T + t011*rh_i
                // phi==0 for invalid lanes => all products zero => no masking needed on accV
#pragma unroll
                for (int i = 0; i < 3; ++i) {
#pragma unroll
                    for (int mt = 0; mt < 2; ++mt) {
                        float q1[4], q2[4];
#pragma unroll
                        for (int r = 0; r < 4; ++r) {
                            q1[r] = phi[mt][r] * lv[i][mt][r];
                            float cr;
                            if (i == 0)      cr = lv[1][mt][r] * rh2 - lv[2][mt][r] * rh1;
                            else if (i == 1) cr = lv[2][mt][r] * rh0 - lv[0][mt][r] * rh2;
                            else             cr = lv[0][mt][r] * rh1 - lv[1][mt][r] * rh0;
                            q2[r] = phi[mt][r] * cr;
                        }
                        uint2 wa; wa.x = pack2(q1[0], q1[1]); wa.y = pack2(q1[2], q1[3]);
                        *(uint2*)&buf[col * 72 + mt * 16 + quad * 4] = wa;
                        uint2 wb; wb.x = pack2(q2[0], q2[1]); wb.y = pack2(q2[2], q2[3]);
                        *(uint2*)&buf[col * 72 + 32 + mt * 16 + quad * 4] = wb;
                    }
                    f32x4 vacc = zero;
#pragma unroll
                    for (int ks = 0; ks < 2; ++ks) {
                        bf16x8 bb = *(const bf16x8*)&buf[col * 72 + ks * 32 + quad * 8];
                        bf16x8 aa = *(const bf16x8*)&Wlds[OFF_WV + col * 72 + ks * 32 + quad * 8];
                        vacc = __builtin_amdgcn_mfma_f32_16x16x32_bf16(aa, bb, vacc, 0, 0, 0);
                    }
                    float rhi = (i == 0) ? rh0 : (i == 1) ? rh1 : rh2;
#pragma unroll
                    for (int r = 0; r < 4; ++r)
                        accV[r * 3 + i] += 0.1f * (vacc[r] + t011v[r] * rhi);
                }

                // ---- residual MLP on psi_a (3x 64x64 GEMM, leaky_relu 0.1)
#pragma unroll
                for (int mt = 0; mt < 4; ++mt)
                    *(uint2*)&buf[col * 72 + mt * 16 + quad * 4] = psiPk[mt];
                // layer 1
                f32x4 hacc[4] = {zero, zero, zero, zero};
#pragma unroll
                for (int ks = 0; ks < 2; ++ks) {
                    bf16x8 bb = *(const bf16x8*)&buf[col * 72 + ks * 32 + quad * 8];
#pragma unroll
                    for (int mt = 0; mt < 4; ++mt) {
                        bf16x8 aa = *(const bf16x8*)&Wlds[OFF_WM1 + (mt * 16 + col) * 72 + ks * 32 + quad * 8];
                        hacc[mt] = __builtin_amdgcn_mfma_f32_16x16x32_bf16(aa, bb, hacc[mt], 0, 0, 0);
                    }
                }
#pragma unroll
                for (int mt = 0; mt < 4; ++mt) {
                    float h[4];
#pragma unroll
                    for (int r = 0; r < 4; ++r) {
                        float x = hacc[mt][r] + Bias[32 + mt * 16 + quad * 4 + r];
                        h[r] = fmaxf(x, 0.1f * x);
                    }
                    uint2 w; w.x = pack2(h[0], h[1]); w.y = pack2(h[2], h[3]);
                    *(uint2*)&buf[col * 72 + mt * 16 + quad * 4] = w;
                }
                // layer 2
                f32x4 gacc[4] = {zero, zero, zero, zero};
#pragma unroll
                for (int ks = 0; ks < 2; ++ks) {
                    bf16x8 bb = *(const bf16x8*)&buf[col * 72 + ks * 32 + quad * 8];
#pragma unroll
                    for (int mt = 0; mt < 4; ++mt) {
                        bf16x8 aa = *(const bf16x8*)&Wlds[OFF_WM2 + (mt * 16 + col) * 72 + ks * 32 + quad * 8];
                        gacc[mt] = __builtin_amdgcn_mfma_f32_16x16x32_bf16(aa, bb, gacc[mt], 0, 0, 0);
                    }
                }
#pragma unroll
                for (int mt = 0; mt < 4; ++mt) {
                    float h[4];
#pragma unroll
                    for (int r = 0; r < 4; ++r) {
                        float x = gacc[mt][r] + Bias[96 + mt * 16 + quad * 4 + r];
                        h[r] = fmaxf(x, 0.1f * x);
                    }
                    uint2 w; w.x = pack2(h[0], h[1]); w.y = pack2(h[2], h[3]);
                    *(uint2*)&buf[col * 72 + mt * 16 + quad * 4] = w;
                }
                // layer 3 (no bias) + scale + accumulate (masked via validf; psi already folded)
                f32x4 oacc[4] = {zero, zero, zero, zero};
#pragma unroll
                for (int ks = 0; ks < 2; ++ks) {
                    bf16x8 bb = *(const bf16x8*)&buf[col * 72 + ks * 32 + quad * 8];
#pragma unroll
                    for (int mt = 0; mt < 4; ++mt) {
                        bf16x8 aa = *(const bf16x8*)&Wlds[OFF_WM3 + (mt * 16 + col) * 72 + ks * 32 + quad * 8];
                        oacc[mt] = __builtin_amdgcn_mfma_f32_16x16x32_bf16(aa, bb, oacc[mt], 0, 0, 0);
                    }
                }
#pragma unroll
                for (int mt = 0; mt < 4; ++mt)
#pragma unroll
                    for (int r = 0; r < 4; ++r)
                        accA[mt][r] = fmaf(0.1f * oacc[mt][r], validf, accA[mt][r]);

                nd = ndn; r0 = nr0; r1 = nr1; r2 = nr2;
            }
        }

        // ---- butterfly reduction across the 16 cols (lanes quad*16 + col)
#pragma unroll
        for (int d2 = 1; d2 < 16; d2 <<= 1) {
#pragma unroll
            for (int mt = 0; mt < 4; ++mt)
#pragma unroll
                for (int r = 0; r < 4; ++r) accA[mt][r] += __shfl_xor(accA[mt][r], d2);
#pragma unroll
            for (int j = 0; j < 12; ++j) accV[j] += __shfl_xor(accV[j], d2);
        }

        // ---- store (col 0 lanes: one per quad)
        if (col == 0) {
#pragma unroll
            for (int mt = 0; mt < 4; ++mt) {
                float4 st = {accA[mt][0], accA[mt][1], accA[mt][2], accA[mt][3]};
                *(float4*)&outA[(size_t)n * 64 + mt * 16 + quad * 4] = st;
            }
#pragma unroll
            for (int j = 0; j < 3; ++j) {
                float4 st = {accV[j * 4 + 0], accV[j * 4 + 1], accV[j * 4 + 2], accV[j * 4 + 3]};
                *(float4*)&outV[(size_t)n * 48 + quad * 12 + j * 4] = st;
            }
        }
    }
}

extern "C" void kernel_launch(void* const* d_in, const int* in_sizes, int n_in,
                              void* d_out, int out_size, void* d_ws, size_t ws_size,
                              hipStream_t stream) {
    const float* r_ij  = (const float*)d_in[0];
    const float* x_a   = (const float*)d_in[1];
    const float* x_v   = (const float*)d_in[2];
    const int*   src   = (const int*)d_in[3];
    const int*   dst   = (const int*)d_in[4];
    const float* W_L0  = (const float*)d_in[5];
    const float* W_L1  = (const float*)d_in[6];
    const float* W_enc = (const float*)d_in[7];
    const float* b_enc = (const float*)d_in[8];
    const float* WY000 = (const float*)d_in[9];
    const float* WY110 = (const float*)d_in[10];
    const float* WY011 = (const float*)d_in[11];
    const float* WY101 = (const float*)d_in[12];
    const float* WY111 = (const float*)d_in[13];
    const float* Wm1   = (const float*)d_in[14];
    const float* bm1   = (const float*)d_in[15];
    const float* Wm2   = (const float*)d_in[16];
    const float* bm2   = (const float*)d_in[17];
    const float* Wm3   = (const float*)d_in[18];
    float* out = (float*)d_out;

    char* ws = (char*)d_ws;
    unsigned short* rec = (unsigned short*)(ws + REC_OFF);
    int* cnt            = (int*)(ws + CNT_OFF);
    int* ell            = (int*)(ws + ELL_OFF);

    hipMemsetAsync(d_out, 0, (size_t)out_size * sizeof(float), stream);
    hipMemsetAsync(cnt, 0, N_NODES * sizeof(int), stream);

    node_kernel<<<(N_NODES * 32) / 256, 256, 0, stream>>>(x_a, x_v, W_L0, W_L1, rec);
    ell_kernel<<<(N_EDGES + 255) / 256, 256, 0, stream>>>(src, cnt, ell);
    node_major_kernel<<<2048, 256, 0, stream>>>(r_ij, dst, W_enc, b_enc,
            WY000, WY110, WY011, WY101, WY111, Wm1, bm1, Wm2, bm2, Wm3,
            rec, cnt, ell, out);
}

// Round 8
// 503.066 us; speedup vs baseline: 2.0301x; 1.1737x over previous
//
#include <hip/hip_runtime.h>

typedef __bf16 bf16x8 __attribute__((ext_vector_type(8)));
typedef __bf16 bf16x2 __attribute__((ext_vector_type(2)));
typedef float f32x4 __attribute__((ext_vector_type(4)));

#define N_NODES 50000
#define N_EDGES 800000
#define MAXDEG 128
#define NODE_STRIDE 2048          // grid 512 blocks x 4 waves
#define BA_OFF 0
#define BV_OFF (N_NODES * 64)

// ---- workspace layout (byte offsets)
#define REC_OFF   0ull            // 50000*128 bf16 = 12.8 MB node records
#define CNT_OFF   12800000ull     // 50000 int degree counts
#define ELLP_OFF  13200384ull     // 50000*128 int4 packed {r0,r1,r2,dst} = 102.4 MB

// ---- LDS weight layout (ushort units). K=64 rows padded to 72, K=32 rows to 40
#define OFF_WFOLD 0              // 32 x 40
#define OFF_WCAT  1280           // 64 x 72  [WY000 | WY110]
#define OFF_W011  5888           // 16 x 40
#define OFF_WV    6528           // 16 x 72  [WY101 | WY111]
#define OFF_WM1   7680           // 64 x 72
#define OFF_WM2   12288
#define OFF_WM3   16896
#define W_USHORTS 21504

#if defined(__has_builtin)
#if __has_builtin(__builtin_amdgcn_cvt_pk_bf16_f32)
#define HAVE_PK_BF16 1
#endif
#endif

__device__ __forceinline__ unsigned short f2bf(float x) {
    unsigned u = __float_as_uint(x);
    return (unsigned short)((u + 0x7FFFu + ((u >> 16) & 1u)) >> 16);
}
__device__ __forceinline__ unsigned pack2(float a, float b) {
#ifdef HAVE_PK_BF16
    union { bf16x2 h; unsigned u; } cv;
    cv.h = __builtin_amdgcn_cvt_pk_bf16_f32(a, b);
    return cv.u;
#else
    return (unsigned)f2bf(a) | ((unsigned)f2bf(b) << 16);
#endif
}
__device__ __forceinline__ float bf2f(unsigned short h) {
    return __uint_as_float(((unsigned)h) << 16);
}

// ---------------- node features + cnt zeroing
__global__ __launch_bounds__(256) void node_kernel(
    const float* __restrict__ x_a, const float* __restrict__ x_v,
    const float* __restrict__ W_L0, const float* __restrict__ W_L1,
    unsigned short* __restrict__ rec, int* __restrict__ cnt)
{
    int t = blockIdx.x * 256 + threadIdx.x;
    if (t >= N_NODES * 32) return;
    if (t < N_NODES) cnt[t] = 0;
    int n = t >> 5, c = t & 31;
    const float* xa = x_a + (size_t)n * 64;
    const float* w0 = W_L0 + c * 64;
    float accA = 0.f;
#pragma unroll
    for (int k = 0; k < 64; ++k) accA += xa[k] * w0[k];
    const float* xv = x_v + (size_t)n * 48;
    const float* w1 = W_L1 + c * 16;
    float a0 = 0.f, a1 = 0.f, a2 = 0.f;
#pragma unroll
    for (int d = 0; d < 16; ++d) {
        float w = w1[d];
        a0 += xv[d * 3 + 0] * w;
        a1 += xv[d * 3 + 1] * w;
        a2 += xv[d * 3 + 2] * w;
    }
    unsigned short* rp = rec + (size_t)n * 128;
    rp[c]      = f2bf(accA);
    rp[32 + c] = f2bf(a0);
    rp[64 + c] = f2bf(a1);
    rp[96 + c] = f2bf(a2);
}

// ---------------- packed ELL build: each slot gets {r0,r1,r2,dst} (16B)
__global__ __launch_bounds__(256) void ell_kernel(
    const int* __restrict__ src, const int* __restrict__ dst,
    const float* __restrict__ r_ij, int* __restrict__ cnt, int4* __restrict__ ellp)
{
    int e = blockIdx.x * 256 + threadIdx.x;
    if (e >= N_EDGES) return;
    int s = src[e];
    int o = atomicAdd(&cnt[s], 1);
    if (o < MAXDEG) {
        int4 v;
        v.x = __float_as_int(r_ij[e * 3 + 0]);
        v.y = __float_as_int(r_ij[e * 3 + 1]);
        v.z = __float_as_int(r_ij[e * 3 + 2]);
        v.w = dst[e];
        ellp[(size_t)s * MAXDEG + o] = v;
    }
}

// ---------------- node-major fused kernel, 2-deep software pipeline over tiles
__global__ __launch_bounds__(256, 1) void node_major_kernel(
    const int4* __restrict__ ellp,
    const float* __restrict__ W_enc, const float* __restrict__ b_enc,
    const float* __restrict__ WY000, const float* __restrict__ WY110,
    const float* __restrict__ WY011, const float* __restrict__ WY101, const float* __restrict__ WY111,
    const float* __restrict__ Wm1, const float* __restrict__ bm1,
    const float* __restrict__ Wm2, const float* __restrict__ bm2,
    const float* __restrict__ Wm3,
    const unsigned short* __restrict__ rec,
    const int* __restrict__ cnt,
    float* __restrict__ out)
{
    __shared__ __align__(16) unsigned short Wlds[W_USHORTS];
    __shared__ __align__(16) unsigned short Buf[4][3456];   // 3 regions x (16x72) per wave
    __shared__ __align__(16) float Bias[160];

    const int tid = threadIdx.x;

    // ---- stage weights to LDS (bf16), fold W_enc over duplicated coeffs
    for (int idx = tid; idx < 1024; idx += 256) {
        int c = idx >> 5, k = idx & 31;
        float v;
        if (k < 16) v = W_enc[c * 64 + 2 * k] + W_enc[c * 64 + 2 * k + 1];
        else        v = W_enc[c * 64 + 32 + 2 * (k - 16)] + W_enc[c * 64 + 32 + 2 * (k - 16) + 1];
        Wlds[OFF_WFOLD + c * 40 + k] = f2bf(v);
    }
    for (int idx = tid; idx < 4096; idx += 256) {
        int d = idx >> 6, k = idx & 63;
        float v = (k < 32) ? WY000[d * 32 + k] : WY110[d * 32 + (k - 32)];
        Wlds[OFF_WCAT + d * 72 + k] = f2bf(v);
        Wlds[OFF_WM1 + d * 72 + k] = f2bf(Wm1[d * 64 + k]);
        Wlds[OFF_WM2 + d * 72 + k] = f2bf(Wm2[d * 64 + k]);
        Wlds[OFF_WM3 + d * 72 + k] = f2bf(Wm3[d * 64 + k]);
    }
    for (int idx = tid; idx < 512; idx += 256) {
        int vv = idx >> 5, k = idx & 31;
        Wlds[OFF_W011 + vv * 40 + k] = f2bf(WY011[vv * 32 + k]);
    }
    for (int idx = tid; idx < 1024; idx += 256) {
        int vv = idx >> 6, k = idx & 63;
        float w = (k < 32) ? WY101[vv * 32 + k] : WY111[vv * 32 + (k - 32)];
        Wlds[OFF_WV + vv * 72 + k] = f2bf(w);
    }
    if (tid < 32) Bias[tid] = b_enc[tid];
    if (tid < 64) { Bias[32 + tid] = bm1[tid]; Bias[96 + tid] = bm2[tid]; }
    __syncthreads();

    const int wid  = tid >> 6;
    const int lane = tid & 63;
    const int col  = lane & 15;
    const int quad = lane >> 4;

    unsigned short* R0 = &Buf[wid][0];
    unsigned short* R1 = &Buf[wid][1152];
    unsigned short* R2 = &Buf[wid][2304];

    const f32x4 zero = {0.f, 0.f, 0.f, 0.f};
    float* __restrict__ outA = out + BA_OFF;
    float* __restrict__ outV = out + BV_OFF;

    // ---- pipeline prologue -------------------------------------------------
    int n_cur = blockIdx.x * 4 + wid, j_cur = 0;
    int deg_cur = cnt[n_cur]; deg_cur = (deg_cur < MAXDEG) ? deg_cur : MAXDEG;
    int4 hc = ellp[(size_t)n_cur * MAXDEG + col];

    int n_nxt, j_nxt;
    if (16 < deg_cur) { n_nxt = n_cur; j_nxt = 16; } else { n_nxt = n_cur + NODE_STRIDE; j_nxt = 0; }
    int ns = (n_nxt < N_NODES) ? n_nxt : 0;
    int deg_nxt = cnt[ns]; deg_nxt = (deg_nxt < MAXDEG) ? deg_nxt : MAXDEG;
    int4 hn = ellp[(size_t)ns * MAXDEG + j_nxt + col];

    int n_n2, j_n2;
    if (j_nxt + 16 < deg_nxt) { n_n2 = n_nxt; j_n2 = j_nxt + 16; } else { n_n2 = n_nxt + NODE_STRIDE; j_n2 = 0; }

    // gather q for tile 0
    ushort4 qa0, qa1, qv[6];
    {
        int nd = ((unsigned)hc.w < N_NODES) ? hc.w : 0;
        const unsigned short* rp = rec + (size_t)nd * 128;
        qa0 = *(const ushort4*)&rp[quad * 4];
        qa1 = *(const ushort4*)&rp[16 + quad * 4];
#pragma unroll
        for (int i = 0; i < 3; ++i)
#pragma unroll
            for (int mt = 0; mt < 2; ++mt)
                qv[i * 2 + mt] = *(const ushort4*)&rp[32 + i * 32 + mt * 16 + quad * 4];
    }

    float accA[4][4];
    float accV[12];
#pragma unroll
    for (int mt = 0; mt < 4; ++mt)
#pragma unroll
        for (int r = 0; r < 4; ++r) accA[mt][r] = 0.f;
#pragma unroll
    for (int j = 0; j < 12; ++j) accV[j] = 0.f;

    // ---- main tile loop ----------------------------------------------------
    while (n_cur < N_NODES) {
        // issue head(t+2) + deg(t+2 node) early
        int ns2 = (n_n2 < N_NODES) ? n_n2 : 0;
        int4 h2 = ellp[(size_t)ns2 * MAXDEG + j_n2 + col];
        int deg_n2 = cnt[ns2]; deg_n2 = (deg_n2 < MAXDEG) ? deg_n2 : MAXDEG;

        const float validf = (j_cur + col < deg_cur) ? 1.f : 0.f;

        // ---- per-edge geometry (from packed head, in registers)
        float r0 = __int_as_float(hc.x), r1 = __int_as_float(hc.y), r2 = __int_as_float(hc.z);
        float u  = sqrtf(r0 * r0 + r1 * r1 + r2 * r2);
        float a  = 0.6283185307f * u;
        float s14 = 1.4f * u;
        float th  = tanhf(s14);
        float f   = th / fmaxf(s14, 1e-12f);
        float rh0 = 1.4f * r0 * f, rh1 = 1.4f * r1 * f, rh2 = 1.4f * r2 * f;

        // ---- radial features
        float c1 = cosf(a), s1 = sinf(a);
        float c2 = c1 * c1 - s1 * s1, s2 = 2.f * c1 * s1;
        float c4 = c2 * c2 - s2 * s2, s4 = 2.f * c2 * s2;
        float c8 = c4 * c4 - s4 * s4, s8 = 2.f * c4 * s4;
        float cc, ss;
        if (quad & 1) { cc = c8 * c1 - s8 * s1; ss = s8 * c1 + c8 * s1; }
        else          { cc = c1; ss = s1; }
        float rvf[8];
        bool usec = (quad < 2);
#pragma unroll
        for (int jj = 0; jj < 8; ++jj) {
            rvf[jj] = usec ? cc : ss;
            float cn = cc * c1 - ss * s1; ss = ss * c1 + cc * s1; cc = cn;
        }
        union { unsigned u4[4]; bf16x8 v; } brU;
        brU.u4[0] = pack2(rvf[0], rvf[1]);
        brU.u4[1] = pack2(rvf[2], rvf[3]);
        brU.u4[2] = pack2(rvf[4], rvf[5]);
        brU.u4[3] = pack2(rvf[6], rvf[7]);
        bf16x8 brad = brU.v;

        // ---- phi GEMM
        float phi[2][4];
#pragma unroll
        for (int mt = 0; mt < 2; ++mt) {
            bf16x8 aw = *(const bf16x8*)&Wlds[OFF_WFOLD + (mt * 16 + col) * 40 + quad * 8];
            f32x4 pa = __builtin_amdgcn_mfma_f32_16x16x32_bf16(aw, brad, zero, 0, 0, 0);
#pragma unroll
            for (int r = 0; r < 4; ++r)
                phi[mt][r] = (pa[r] + Bias[mt * 16 + quad * 4 + r]) * validf;
        }

        // ---- order-0 tensor products -> R0 = [y000 | y110] (inline unpack)
#pragma unroll
        for (int mt = 0; mt < 2; ++mt) {
            const ushort4 qa = (mt == 0) ? qa0 : qa1;
            float laf[4] = {bf2f(qa.x), bf2f(qa.y), bf2f(qa.z), bf2f(qa.w)};
            float y0[4], y1[4];
#pragma unroll
            for (int r = 0; r < 4; ++r) {
                const unsigned short* px = (const unsigned short*)&qv[0 * 2 + mt];
                const unsigned short* py = (const unsigned short*)&qv[1 * 2 + mt];
                const unsigned short* pz = (const unsigned short*)&qv[2 * 2 + mt];
                float dotv = bf2f(px[r]) * rh0 + bf2f(py[r]) * rh1 + bf2f(pz[r]) * rh2;
                y0[r] = laf[r] * phi[mt][r];
                y1[r] = phi[mt][r] * dotv;
            }
            uint2 w0; w0.x = pack2(y0[0], y0[1]); w0.y = pack2(y0[2], y0[3]);
            *(uint2*)&R0[col * 72 + mt * 16 + quad * 4] = w0;
            uint2 w1; w1.x = pack2(y1[0], y1[1]); w1.y = pack2(y1[2], y1[3]);
            *(uint2*)&R0[col * 72 + 32 + mt * 16 + quad * 4] = w1;
        }

        // ---- psi_a = [y000|y110] @ [WY000|WY110].T
        f32x4 pacc[4] = {zero, zero, zero, zero};
#pragma unroll
        for (int ks = 0; ks < 2; ++ks) {
            bf16x8 bb = *(const bf16x8*)&R0[col * 72 + ks * 32 + quad * 8];
#pragma unroll
            for (int mt = 0; mt < 4; ++mt) {
                bf16x8 aa = *(const bf16x8*)&Wlds[OFF_WCAT + (mt * 16 + col) * 72 + ks * 32 + quad * 8];
                pacc[mt] = __builtin_amdgcn_mfma_f32_16x16x32_bf16(aa, bb, pacc[mt], 0, 0, 0);
            }
        }
        uint2 psiPk[4];
#pragma unroll
        for (int mt = 0; mt < 4; ++mt) {
#pragma unroll
            for (int r = 0; r < 4; ++r)
                accA[mt][r] = fmaf(0.1f * pacc[mt][r], validf, accA[mt][r]);
            psiPk[mt].x = pack2(pacc[mt][0], pacc[mt][1]);
            psiPk[mt].y = pack2(pacc[mt][2], pacc[mt][3]);
        }

        // ---- t011 = y000 @ WY011.T  [R0 still holds ya]
        bf16x8 b0 = *(const bf16x8*)&R0[col * 72 + quad * 8];
        bf16x8 a011 = *(const bf16x8*)&Wlds[OFF_W011 + col * 40 + quad * 8];
        f32x4 t011v = __builtin_amdgcn_mfma_f32_16x16x32_bf16(a011, b0, zero, 0, 0, 0);

        // ---- mid-body: issue rec gather for NEXT tile (head loaded a full tile ago)
        ushort4 nqa0, nqa1, nqv[6];
        {
            int ndn = ((unsigned)hn.w < N_NODES) ? hn.w : 0;
            const unsigned short* rpn = rec + (size_t)ndn * 128;
            nqa0 = *(const ushort4*)&rpn[quad * 4];
            nqa1 = *(const ushort4*)&rpn[16 + quad * 4];
#pragma unroll
            for (int i = 0; i < 3; ++i)
#pragma unroll
                for (int mt = 0; mt < 2; ++mt)
                    nqv[i * 2 + mt] = *(const ushort4*)&rpn[32 + i * 32 + mt * 16 + quad * 4];
        }

        // ---- unpack lv (yv-section live range only)
        float lv[3][2][4];
#pragma unroll
        for (int i = 0; i < 3; ++i)
#pragma unroll
            for (int mt = 0; mt < 2; ++mt) {
                ushort4 p = qv[i * 2 + mt];
                lv[i][mt][0] = bf2f(p.x); lv[i][mt][1] = bf2f(p.y);
                lv[i][mt][2] = bf2f(p.z); lv[i][mt][3] = bf2f(p.w);
            }

        // ---- psi_v: batched writes (i0->R1, i1->R2, i2->R0), then 3 MFMA chains
        unsigned short* const yvR[3] = {R1, R2, R0};
#pragma unroll
        for (int i = 0; i < 3; ++i) {
#pragma unroll
            for (int mt = 0; mt < 2; ++mt) {
                float q1[4], q2[4];
#pragma unroll
                for (int r = 0; r < 4; ++r) {
                    q1[r] = phi[mt][r] * lv[i][mt][r];
                    float cr;
                    if (i == 0)      cr = lv[1][mt][r] * rh2 - lv[2][mt][r] * rh1;
                    else if (i == 1) cr = lv[2][mt][r] * rh0 - lv[0][mt][r] * rh2;
                    else             cr = lv[0][mt][r] * rh1 - lv[1][mt][r] * rh0;
                    q2[r] = phi[mt][r] * cr;
                }
                uint2 wa; wa.x = pack2(q1[0], q1[1]); wa.y = pack2(q1[2], q1[3]);
                *(uint2*)&yvR[i][col * 72 + mt * 16 + quad * 4] = wa;
                uint2 wb; wb.x = pack2(q2[0], q2[1]); wb.y = pack2(q2[2], q2[3]);
                *(uint2*)&yvR[i][col * 72 + 32 + mt * 16 + quad * 4] = wb;
            }
        }
        f32x4 vacc[3] = {zero, zero, zero};
#pragma unroll
        for (int i = 0; i < 3; ++i)
#pragma unroll
            for (int ks = 0; ks < 2; ++ks) {
                bf16x8 bb = *(const bf16x8*)&yvR[i][col * 72 + ks * 32 + quad * 8];
                bf16x8 aa = *(const bf16x8*)&Wlds[OFF_WV + col * 72 + ks * 32 + quad * 8];
                vacc[i] = __builtin_amdgcn_mfma_f32_16x16x32_bf16(aa, bb, vacc[i], 0, 0, 0);
            }
#pragma unroll
        for (int i = 0; i < 3; ++i) {
            float rhi = (i == 0) ? rh0 : (i == 1) ? rh1 : rh2;
#pragma unroll
            for (int r = 0; r < 4; ++r)
                accV[r * 3 + i] += 0.1f * (vacc[i][r] + t011v[r] * rhi);
        }

        // ---- residual MLP (psiPk -> R1; h1 -> R2; h2 -> R1)
#pragma unroll
        for (int mt = 0; mt < 4; ++mt)
            *(uint2*)&R1[col * 72 + mt * 16 + quad * 4] = psiPk[mt];
        f32x4 hacc[4] = {zero, zero, zero, zero};
#pragma unroll
        for (int ks = 0; ks < 2; ++ks) {
            bf16x8 bb = *(const bf16x8*)&R1[col * 72 + ks * 32 + quad * 8];
#pragma unroll
            for (int mt = 0; mt < 4; ++mt) {
                bf16x8 aa = *(const bf16x8*)&Wlds[OFF_WM1 + (mt * 16 + col) * 72 + ks * 32 + quad * 8];
                hacc[mt] = __builtin_amdgcn_mfma_f32_16x16x32_bf16(aa, bb, hacc[mt], 0, 0, 0);
            }
        }
#pragma unroll
        for (int mt = 0; mt < 4; ++mt) {
            float h[4];
#pragma unroll
            for (int r = 0; r < 4; ++r) {
                float x = hacc[mt][r] + Bias[32 + mt * 16 + quad * 4 + r];
                h[r] = fmaxf(x, 0.1f * x);
            }
            uint2 w; w.x = pack2(h[0], h[1]); w.y = pack2(h[2], h[3]);
            *(uint2*)&R2[col * 72 + mt * 16 + quad * 4] = w;
        }
        f32x4 gacc[4] = {zero, zero, zero, zero};
#pragma unroll
        for (int ks = 0; ks < 2; ++ks) {
            bf16x8 bb = *(const bf16x8*)&R2[col * 72 + ks * 32 + quad * 8];
#pragma unroll
            for (int mt = 0; mt < 4; ++mt) {
                bf16x8 aa = *(const bf16x8*)&Wlds[OFF_WM2 + (mt * 16 + col) * 72 + ks * 32 + quad * 8];
                gacc[mt] = __builtin_amdgcn_mfma_f32_16x16x32_bf16(aa, bb, gacc[mt], 0, 0, 0);
            }
        }
#pragma unroll
        for (int mt = 0; mt < 4; ++mt) {
            float h[4];
#pragma unroll
            for (int r = 0; r < 4; ++r) {
                float x = gacc[mt][r] + Bias[96 + mt * 16 + quad * 4 + r];
                h[r] = fmaxf(x, 0.1f * x);
            }
            uint2 w; w.x = pack2(h[0], h[1]); w.y = pack2(h[2], h[3]);
            *(uint2*)&R1[col * 72 + mt * 16 + quad * 4] = w;
        }
        f32x4 oacc[4] = {zero, zero, zero, zero};
#pragma unroll
        for (int ks = 0; ks < 2; ++ks) {
            bf16x8 bb = *(const bf16x8*)&R1[col * 72 + ks * 32 + quad * 8];
#pragma unroll
            for (int mt = 0; mt < 4; ++mt) {
                bf16x8 aa = *(const bf16x8*)&Wlds[OFF_WM3 + (mt * 16 + col) * 72 + ks * 32 + quad * 8];
                oacc[mt] = __builtin_amdgcn_mfma_f32_16x16x32_bf16(aa, bb, oacc[mt], 0, 0, 0);
            }
        }
#pragma unroll
        for (int mt = 0; mt < 4; ++mt)
#pragma unroll
            for (int r = 0; r < 4; ++r)
                accA[mt][r] = fmaf(0.1f * oacc[mt][r], validf, accA[mt][r]);

        // ---- node boundary: reduce + store + reset
        if (n_nxt != n_cur) {
#pragma unroll
            for (int d2 = 1; d2 < 16; d2 <<= 1) {
#pragma unroll
                for (int mt = 0; mt < 4; ++mt)
#pragma unroll
                    for (int r = 0; r < 4; ++r) accA[mt][r] += __shfl_xor(accA[mt][r], d2);
#pragma unroll
                for (int j = 0; j < 12; ++j) accV[j] += __shfl_xor(accV[j], d2);
            }
            if (col == 0) {
#pragma unroll
                for (int mt = 0; mt < 4; ++mt) {
                    float4 st = {accA[mt][0], accA[mt][1], accA[mt][2], accA[mt][3]};
                    *(float4*)&outA[(size_t)n_cur * 64 + mt * 16 + quad * 4] = st;
                }
#pragma unroll
                for (int j = 0; j < 3; ++j) {
                    float4 st = {accV[j * 4 + 0], accV[j * 4 + 1], accV[j * 4 + 2], accV[j * 4 + 3]};
                    *(float4*)&outV[(size_t)n_cur * 48 + quad * 12 + j * 4] = st;
                }
            }
#pragma unroll
            for (int mt = 0; mt < 4; ++mt)
#pragma unroll
                for (int r = 0; r < 4; ++r) accA[mt][r] = 0.f;
#pragma unroll
            for (int j = 0; j < 12; ++j) accV[j] = 0.f;
        }

        // ---- pipeline shift
        n_cur = n_nxt; j_cur = j_nxt; deg_cur = deg_nxt; hc = hn;
        qa0 = nqa0; qa1 = nqa1;
#pragma unroll
        for (int i = 0; i < 6; ++i) qv[i] = nqv[i];
        n_nxt = n_n2; j_nxt = j_n2; deg_nxt = deg_n2; hn = h2;
        if (j_nxt + 16 < deg_nxt) { n_n2 = n_nxt; j_n2 = j_nxt + 16; }
        else                      { n_n2 = n_nxt + NODE_STRIDE; j_n2 = 0; }
    }
}

extern "C" void kernel_launch(void* const* d_in, const int* in_sizes, int n_in,
                              void* d_out, int out_size, void* d_ws, size_t ws_size,
                              hipStream_t stream) {
    const float* r_ij  = (const float*)d_in[0];
    const float* x_a   = (const float*)d_in[1];
    const float* x_v   = (const float*)d_in[2];
    const int*   src   = (const int*)d_in[3];
    const int*   dst   = (const int*)d_in[4];
    const float* W_L0  = (const float*)d_in[5];
    const float* W_L1  = (const float*)d_in[6];
    const float* W_enc = (const float*)d_in[7];
    const float* b_enc = (const float*)d_in[8];
    const float* WY000 = (const float*)d_in[9];
    const float* WY110 = (const float*)d_in[10];
    const float* WY011 = (const float*)d_in[11];
    const float* WY101 = (const float*)d_in[12];
    const float* WY111 = (const float*)d_in[13];
    const float* Wm1   = (const float*)d_in[14];
    const float* bm1   = (const float*)d_in[15];
    const float* Wm2   = (const float*)d_in[16];
    const float* bm2   = (const float*)d_in[17];
    const float* Wm3   = (const float*)d_in[18];
    float* out = (float*)d_out;

    char* ws = (char*)d_ws;
    unsigned short* rec = (unsigned short*)(ws + REC_OFF);
    int* cnt            = (int*)(ws + CNT_OFF);
    int4* ellp          = (int4*)(ws + ELLP_OFF);

    node_kernel<<<(N_NODES * 32) / 256, 256, 0, stream>>>(x_a, x_v, W_L0, W_L1, rec, cnt);
    ell_kernel<<<(N_EDGES + 255) / 256, 256, 0, stream>>>(src, dst, r_ij, cnt, ellp);
    node_major_kernel<<<512, 256, 0, stream>>>(ellp, W_enc, b_enc,
            WY000, WY110, WY011, WY101, WY111, Wm1, bm1, Wm2, bm2, Wm3,
            rec, cnt, out);
}

// Round 9
// 498.196 us; speedup vs baseline: 2.0499x; 1.0098x over previous
//
#include <hip/hip_runtime.h>

typedef __bf16 bf16x8 __attribute__((ext_vector_type(8)));
typedef __bf16 bf16x2 __attribute__((ext_vector_type(2)));
typedef float f32x4 __attribute__((ext_vector_type(4)));

#define N_NODES 50000
#define N_EDGES 800000
#define MAXDEG 128
#define NODE_STRIDE 3072          // grid 768 blocks x 4 waves
#define BA_OFF 0
#define BV_OFF (N_NODES * 64)

// ---- workspace layout (byte offsets)
#define REC_OFF   0ull            // 50000*128 bf16 = 12.8 MB node records
#define CNT_OFF   12800000ull     // 50000 int degree counts
#define ELLP_OFF  13200384ull     // 50000*128 int4 packed {r0,r1,r2,dst} = 102.4 MB

// ---- LDS weight layout (ushort units). K=64 rows padded to 72, K=32 rows to 40
#define OFF_WFOLD 0              // 32 x 40
#define OFF_WCAT  1280           // 64 x 72  [WY000 | WY110]
#define OFF_W011  5888           // 16 x 40
#define OFF_WV    6528           // 16 x 72  [WY101 | WY111]
#define OFF_WM1   7680           // 64 x 72
#define OFF_WM2   12288
#define OFF_WM3   16896
#define W_USHORTS 21504

#if defined(__has_builtin)
#if __has_builtin(__builtin_amdgcn_cvt_pk_bf16_f32)
#define HAVE_PK_BF16 1
#endif
#endif

__device__ __forceinline__ unsigned short f2bf(float x) {
    unsigned u = __float_as_uint(x);
    return (unsigned short)((u + 0x7FFFu + ((u >> 16) & 1u)) >> 16);
}
__device__ __forceinline__ unsigned pack2(float a, float b) {
#ifdef HAVE_PK_BF16
    union { bf16x2 h; unsigned u; } cv;
    cv.h = __builtin_amdgcn_cvt_pk_bf16_f32(a, b);
    return cv.u;
#else
    return (unsigned)f2bf(a) | ((unsigned)f2bf(b) << 16);
#endif
}
__device__ __forceinline__ float bf2f(unsigned short h) {
    return __uint_as_float(((unsigned)h) << 16);
}

// ---------------- node features + cnt zeroing
__global__ __launch_bounds__(256) void node_kernel(
    const float* __restrict__ x_a, const float* __restrict__ x_v,
    const float* __restrict__ W_L0, const float* __restrict__ W_L1,
    unsigned short* __restrict__ rec, int* __restrict__ cnt)
{
    int t = blockIdx.x * 256 + threadIdx.x;
    if (t >= N_NODES * 32) return;
    if (t < N_NODES) cnt[t] = 0;
    int n = t >> 5, c = t & 31;
    const float* xa = x_a + (size_t)n * 64;
    const float* w0 = W_L0 + c * 64;
    float accA = 0.f;
#pragma unroll
    for (int k = 0; k < 64; ++k) accA += xa[k] * w0[k];
    const float* xv = x_v + (size_t)n * 48;
    const float* w1 = W_L1 + c * 16;
    float a0 = 0.f, a1 = 0.f, a2 = 0.f;
#pragma unroll
    for (int d = 0; d < 16; ++d) {
        float w = w1[d];
        a0 += xv[d * 3 + 0] * w;
        a1 += xv[d * 3 + 1] * w;
        a2 += xv[d * 3 + 2] * w;
    }
    unsigned short* rp = rec + (size_t)n * 128;
    rp[c]      = f2bf(accA);
    rp[32 + c] = f2bf(a0);
    rp[64 + c] = f2bf(a1);
    rp[96 + c] = f2bf(a2);
}

// ---------------- packed ELL build: each slot gets {r0,r1,r2,dst} (16B)
__global__ __launch_bounds__(256) void ell_kernel(
    const int* __restrict__ src, const int* __restrict__ dst,
    const float* __restrict__ r_ij, int* __restrict__ cnt, int4* __restrict__ ellp)
{
    int e = blockIdx.x * 256 + threadIdx.x;
    if (e >= N_EDGES) return;
    int s = src[e];
    int o = atomicAdd(&cnt[s], 1);
    if (o < MAXDEG) {
        int4 v;
        v.x = __float_as_int(r_ij[e * 3 + 0]);
        v.y = __float_as_int(r_ij[e * 3 + 1]);
        v.z = __float_as_int(r_ij[e * 3 + 2]);
        v.w = dst[e];
        ellp[(size_t)s * MAXDEG + o] = v;
    }
}

// ---------------- node-major fused kernel
// LDS 52.9 KB -> 3 blocks/CU; target VGPR <= 170 for 3 waves/SIMD (12 waves/CU).
__global__ __launch_bounds__(256, 1) void node_major_kernel(
    const int4* __restrict__ ellp,
    const float* __restrict__ W_enc, const float* __restrict__ b_enc,
    const float* __restrict__ WY000, const float* __restrict__ WY110,
    const float* __restrict__ WY011, const float* __restrict__ WY101, const float* __restrict__ WY111,
    const float* __restrict__ Wm1, const float* __restrict__ bm1,
    const float* __restrict__ Wm2, const float* __restrict__ bm2,
    const float* __restrict__ Wm3,
    const unsigned short* __restrict__ rec,
    const int* __restrict__ cnt,
    float* __restrict__ out)
{
    __shared__ __align__(16) unsigned short Wlds[W_USHORTS];
    __shared__ __align__(16) unsigned short Buf[4][1152];   // ONE 16x72 region per wave
    __shared__ __align__(16) float Bias[160];

    const int tid = threadIdx.x;

    // ---- stage weights to LDS (bf16), fold W_enc over duplicated coeffs
    for (int idx = tid; idx < 1024; idx += 256) {
        int c = idx >> 5, k = idx & 31;
        float v;
        if (k < 16) v = W_enc[c * 64 + 2 * k] + W_enc[c * 64 + 2 * k + 1];
        else        v = W_enc[c * 64 + 32 + 2 * (k - 16)] + W_enc[c * 64 + 32 + 2 * (k - 16) + 1];
        Wlds[OFF_WFOLD + c * 40 + k] = f2bf(v);
    }
    for (int idx = tid; idx < 4096; idx += 256) {
        int d = idx >> 6, k = idx & 63;
        float v = (k < 32) ? WY000[d * 32 + k] : WY110[d * 32 + (k - 32)];
        Wlds[OFF_WCAT + d * 72 + k] = f2bf(v);
        Wlds[OFF_WM1 + d * 72 + k] = f2bf(Wm1[d * 64 + k]);
        Wlds[OFF_WM2 + d * 72 + k] = f2bf(Wm2[d * 64 + k]);
        Wlds[OFF_WM3 + d * 72 + k] = f2bf(Wm3[d * 64 + k]);
    }
    for (int idx = tid; idx < 512; idx += 256) {
        int vv = idx >> 5, k = idx & 31;
        Wlds[OFF_W011 + vv * 40 + k] = f2bf(WY011[vv * 32 + k]);
    }
    for (int idx = tid; idx < 1024; idx += 256) {
        int vv = idx >> 6, k = idx & 63;
        float w = (k < 32) ? WY101[vv * 32 + k] : WY111[vv * 32 + (k - 32)];
        Wlds[OFF_WV + vv * 72 + k] = f2bf(w);
    }
    if (tid < 32) Bias[tid] = b_enc[tid];
    if (tid < 64) { Bias[32 + tid] = bm1[tid]; Bias[96 + tid] = bm2[tid]; }
    __syncthreads();

    const int wid  = tid >> 6;
    const int lane = tid & 63;
    const int col  = lane & 15;
    const int quad = lane >> 4;

    unsigned short* buf = &Buf[wid][0];

    const f32x4 zero = {0.f, 0.f, 0.f, 0.f};
    float* __restrict__ outA = out + BA_OFF;
    float* __restrict__ outV = out + BV_OFF;

    // ---- prologue
    int n_cur = blockIdx.x * 4 + wid, j_cur = 0;
    int deg_cur = cnt[n_cur]; deg_cur = (deg_cur < MAXDEG) ? deg_cur : MAXDEG;
    int4 hc = ellp[(size_t)n_cur * MAXDEG + col];
    int n_nxt, j_nxt;
    if (16 < deg_cur) { n_nxt = n_cur; j_nxt = 16; } else { n_nxt = n_cur + NODE_STRIDE; j_nxt = 0; }

    float accA[4][4];
    float accV[12];
#pragma unroll
    for (int mt = 0; mt < 4; ++mt)
#pragma unroll
        for (int r = 0; r < 4; ++r) accA[mt][r] = 0.f;
#pragma unroll
    for (int j = 0; j < 12; ++j) accV[j] = 0.f;

    while (n_cur < N_NODES) {
        // ---- current-tile rec gather: hc.w has been in registers for a full tile
        int nd = ((unsigned)hc.w < N_NODES) ? hc.w : 0;
        const unsigned short* rp = rec + (size_t)nd * 128;
        ushort4 qa0 = *(const ushort4*)&rp[quad * 4];
        ushort4 qa1 = *(const ushort4*)&rp[16 + quad * 4];
        ushort4 qv[6];
#pragma unroll
        for (int i = 0; i < 3; ++i)
#pragma unroll
            for (int mt = 0; mt < 2; ++mt)
                qv[i * 2 + mt] = *(const ushort4*)&rp[32 + i * 32 + mt * 16 + quad * 4];

        // ---- next-tile head (16B coalesced) + next deg
        int ns = (n_nxt < N_NODES) ? n_nxt : 0;
        int4 hn = ellp[(size_t)ns * MAXDEG + j_nxt + col];
        int dnx = cnt[ns]; dnx = (dnx < MAXDEG) ? dnx : MAXDEG;

        const float validf = (j_cur + col < deg_cur) ? 1.f : 0.f;

        // ---- per-edge geometry (fast transcendentals)
        float r0 = __int_as_float(hc.x), r1 = __int_as_float(hc.y), r2 = __int_as_float(hc.z);
        float u  = sqrtf(r0 * r0 + r1 * r1 + r2 * r2);
        float a  = 0.6283185307f * u;            // (pi/5) * dist
        float s14 = 1.4f * u;
        // tanh(x)/x == (e^{2x}-1)/((e^{2x}+1)*x) exactly; clamp exp arg to dodge inf/inf
        float e2 = __expf(fminf(2.f * s14, 20.f));
        float f  = (e2 - 1.f) / ((e2 + 1.f) * fmaxf(s14, 1e-12f));
        float rh0 = 1.4f * r0 * f, rh1 = 1.4f * r1 * f, rh2 = 1.4f * r2 * f;

        // ---- radial features: native sincos + dual-chain recurrence
        float c1, s1;
        __sincosf(a, &s1, &c1);
        float c2 = c1 * c1 - s1 * s1, s2 = 2.f * c1 * s1;
        float cc, ss;
        if (quad & 1) {
            float c4 = c2 * c2 - s2 * s2, s4 = 2.f * c2 * s2;
            float c8 = c4 * c4 - s4 * s4, s8 = 2.f * c4 * s4;
            cc = c8 * c1 - s8 * s1; ss = s8 * c1 + c8 * s1;   // harmonic 9
        } else { cc = c1; ss = s1; }                           // harmonic 1
        // two interleaved chains stepping by 2 harmonics (half the dep depth)
        float ca = cc, sa = ss;
        float cb = cc * c1 - ss * s1, sb = ss * c1 + cc * s1;
        bool usec = (quad < 2);
        float rvf[8];
        rvf[0] = usec ? ca : sa;
        rvf[1] = usec ? cb : sb;
#pragma unroll
        for (int st = 0; st < 3; ++st) {
            float can = ca * c2 - sa * s2; sa = sa * c2 + ca * s2; ca = can;
            float cbn = cb * c2 - sb * s2; sb = sb * c2 + cb * s2; cb = cbn;
            rvf[2 + 2 * st] = usec ? ca : sa;
            rvf[3 + 2 * st] = usec ? cb : sb;
        }
        union { unsigned u4[4]; bf16x8 v; } brU;
        brU.u4[0] = pack2(rvf[0], rvf[1]);
        brU.u4[1] = pack2(rvf[2], rvf[3]);
        brU.u4[2] = pack2(rvf[4], rvf[5]);
        brU.u4[3] = pack2(rvf[6], rvf[7]);
        bf16x8 brad = brU.v;

        // ---- phi GEMM
        float phi[2][4];
#pragma unroll
        for (int mt = 0; mt < 2; ++mt) {
            bf16x8 aw = *(const bf16x8*)&Wlds[OFF_WFOLD + (mt * 16 + col) * 40 + quad * 8];
            f32x4 pa = __builtin_amdgcn_mfma_f32_16x16x32_bf16(aw, brad, zero, 0, 0, 0);
#pragma unroll
            for (int r = 0; r < 4; ++r)
                phi[mt][r] = (pa[r] + Bias[mt * 16 + quad * 4 + r]) * validf;
        }

        // ---- order-0 tensor products -> buf = [y000 | y110]
#pragma unroll
        for (int mt = 0; mt < 2; ++mt) {
            const ushort4 qa = (mt == 0) ? qa0 : qa1;
            float laf[4] = {bf2f(qa.x), bf2f(qa.y), bf2f(qa.z), bf2f(qa.w)};
            float y0[4], y1[4];
#pragma unroll
            for (int r = 0; r < 4; ++r) {
                const unsigned short* px = (const unsigned short*)&qv[0 * 2 + mt];
                const unsigned short* py = (const unsigned short*)&qv[1 * 2 + mt];
                const unsigned short* pz = (const unsigned short*)&qv[2 * 2 + mt];
                float dotv = bf2f(px[r]) * rh0 + bf2f(py[r]) * rh1 + bf2f(pz[r]) * rh2;
                y0[r] = laf[r] * phi[mt][r];
                y1[r] = phi[mt][r] * dotv;
            }
            uint2 w0; w0.x = pack2(y0[0], y0[1]); w0.y = pack2(y0[2], y0[3]);
            *(uint2*)&buf[col * 72 + mt * 16 + quad * 4] = w0;
            uint2 w1; w1.x = pack2(y1[0], y1[1]); w1.y = pack2(y1[2], y1[3]);
            *(uint2*)&buf[col * 72 + 32 + mt * 16 + quad * 4] = w1;
        }

        // ---- psi_a
        f32x4 pacc[4] = {zero, zero, zero, zero};
#pragma unroll
        for (int ks = 0; ks < 2; ++ks) {
            bf16x8 bb = *(const bf16x8*)&buf[col * 72 + ks * 32 + quad * 8];
#pragma unroll
            for (int mt = 0; mt < 4; ++mt) {
                bf16x8 aa = *(const bf16x8*)&Wlds[OFF_WCAT + (mt * 16 + col) * 72 + ks * 32 + quad * 8];
                pacc[mt] = __builtin_amdgcn_mfma_f32_16x16x32_bf16(aa, bb, pacc[mt], 0, 0, 0);
            }
        }
        uint2 psiPk[4];
#pragma unroll
        for (int mt = 0; mt < 4; ++mt) {
#pragma unroll
            for (int r = 0; r < 4; ++r)
                accA[mt][r] = fmaf(0.1f * pacc[mt][r], validf, accA[mt][r]);
            psiPk[mt].x = pack2(pacc[mt][0], pacc[mt][1]);
            psiPk[mt].y = pack2(pacc[mt][2], pacc[mt][3]);
        }

        // ---- t011 (buf still holds ya)
        bf16x8 b0 = *(const bf16x8*)&buf[col * 72 + quad * 8];
        bf16x8 a011 = *(const bf16x8*)&Wlds[OFF_W011 + col * 40 + quad * 8];
        f32x4 t011v = __builtin_amdgcn_mfma_f32_16x16x32_bf16(a011, b0, zero, 0, 0, 0);

        // ---- unpack lv
        float lv[3][2][4];
#pragma unroll
        for (int i = 0; i < 3; ++i)
#pragma unroll
            for (int mt = 0; mt < 2; ++mt) {
                ushort4 p = qv[i * 2 + mt];
                lv[i][mt][0] = bf2f(p.x); lv[i][mt][1] = bf2f(p.y);
                lv[i][mt][2] = bf2f(p.z); lv[i][mt][3] = bf2f(p.w);
            }

        // ---- psi_v serialized through the single region
#pragma unroll
        for (int i = 0; i < 3; ++i) {
#pragma unroll
            for (int mt = 0; mt < 2; ++mt) {
                float q1[4], q2[4];
#pragma unroll
                for (int r = 0; r < 4; ++r) {
                    q1[r] = phi[mt][r] * lv[i][mt][r];
                    float cr;
                    if (i == 0)      cr = lv[1][mt][r] * rh2 - lv[2][mt][r] * rh1;
                    else if (i == 1) cr = lv[2][mt][r] * rh0 - lv[0][mt][r] * rh2;
                    else             cr = lv[0][mt][r] * rh1 - lv[1][mt][r] * rh0;
                    q2[r] = phi[mt][r] * cr;
                }
                uint2 wa; wa.x = pack2(q1[0], q1[1]); wa.y = pack2(q1[2], q1[3]);
                *(uint2*)&buf[col * 72 + mt * 16 + quad * 4] = wa;
                uint2 wb; wb.x = pack2(q2[0], q2[1]); wb.y = pack2(q2[2], q2[3]);
                *(uint2*)&buf[col * 72 + 32 + mt * 16 + quad * 4] = wb;
            }
            f32x4 vacc = zero;
#pragma unroll
            for (int ks = 0; ks < 2; ++ks) {
                bf16x8 bb = *(const bf16x8*)&buf[col * 72 + ks * 32 + quad * 8];
                bf16x8 aa = *(const bf16x8*)&Wlds[OFF_WV + col * 72 + ks * 32 + quad * 8];
                vacc = __builtin_amdgcn_mfma_f32_16x16x32_bf16(aa, bb, vacc, 0, 0, 0);
            }
            float rhi = (i == 0) ? rh0 : (i == 1) ? rh1 : rh2;
#pragma unroll
            for (int r = 0; r < 4; ++r)
                accV[r * 3 + i] += 0.1f * (vacc[r] + t011v[r] * rhi);
        }

        // ---- residual MLP
#pragma unroll
        for (int mt = 0; mt < 4; ++mt)
            *(uint2*)&buf[col * 72 + mt * 16 + quad * 4] = psiPk[mt];
        f32x4 hacc[4] = {zero, zero, zero, zero};
#pragma unroll
        for (int ks = 0; ks < 2; ++ks) {
            bf16x8 bb = *(const bf16x8*)&buf[col * 72 + ks * 32 + quad * 8];
#pragma unroll
            for (int mt = 0; mt < 4; ++mt) {
                bf16x8 aa = *(const bf16x8*)&Wlds[OFF_WM1 + (mt * 16 + col) * 72 + ks * 32 + quad * 8];
                hacc[mt] = __builtin_amdgcn_mfma_f32_16x16x32_bf16(aa, bb, hacc[mt], 0, 0, 0);
            }
        }
#pragma unroll
        for (int mt = 0; mt < 4; ++mt) {
            float h[4];
#pragma unroll
            for (int r = 0; r < 4; ++r) {
                float x = hacc[mt][r] + Bias[32 + mt * 16 + quad * 4 + r];
                h[r] = fmaxf(x, 0.1f * x);
            }
            uint2 w; w.x = pack2(h[0], h[1]); w.y = pack2(h[2], h[3]);
            *(uint2*)&buf[col * 72 + mt * 16 + quad * 4] = w;
        }
        f32x4 gacc[4] = {zero, zero, zero, zero};
#pragma unroll
        for (int ks = 0; ks < 2; ++ks) {
            bf16x8 bb = *(const bf16x8*)&buf[col * 72 + ks * 32 + quad * 8];
#pragma unroll
            for (int mt = 0; mt < 4; ++mt) {
                bf16x8 aa = *(const bf16x8*)&Wlds[OFF_WM2 + (mt * 16 + col) * 72 + ks * 32 + quad * 8];
                gacc[mt] = __builtin_amdgcn_mfma_f32_16x16x32_bf16(aa, bb, gacc[mt], 0, 0, 0);
            }
        }
#pragma unroll
        for (int mt = 0; mt < 4; ++mt) {
            float h[4];
#pragma unroll
            for (int r = 0; r < 4; ++r) {
                float x = gacc[mt][r] + Bias[96 + mt * 16 + quad * 4 + r];
                h[r] = fmaxf(x, 0.1f * x);
            }
            uint2 w; w.x = pack2(h[0], h[1]); w.y = pack2(h[2], h[3]);
            *(uint2*)&buf[col * 72 + mt * 16 + quad * 4] = w;
        }
        f32x4 oacc[4] = {zero, zero, zero, zero};
#pragma unroll
        for (int ks = 0; ks < 2; ++ks) {
            bf16x8 bb = *(const bf16x8*)&buf[col * 72 + ks * 32 + quad * 8];
#pragma unroll
            for (int mt = 0; mt < 4; ++mt) {
                bf16x8 aa = *(const bf16x8*)&Wlds[OFF_WM3 + (mt * 16 + col) * 72 + ks * 32 + quad * 8];
                oacc[mt] = __builtin_amdgcn_mfma_f32_16x16x32_bf16(aa, bb, oacc[mt], 0, 0, 0);
            }
        }
#pragma unroll
        for (int mt = 0; mt < 4; ++mt)
#pragma unroll
            for (int r = 0; r < 4; ++r)
                accA[mt][r] = fmaf(0.1f * oacc[mt][r], validf, accA[mt][r]);

        // ---- node boundary: reduce + store + reset
        if (n_nxt != n_cur) {
#pragma unroll
            for (int d2 = 1; d2 < 16; d2 <<= 1) {
#pragma unroll
                for (int mt = 0; mt < 4; ++mt)
#pragma unroll
                    for (int r = 0; r < 4; ++r) accA[mt][r] += __shfl_xor(accA[mt][r], d2);
#pragma unroll
                for (int j = 0; j < 12; ++j) accV[j] += __shfl_xor(accV[j], d2);
            }
            if (col == 0) {
#pragma unroll
                for (int mt = 0; mt < 4; ++mt) {
                    float4 st = {accA[mt][0], accA[mt][1], accA[mt][2], accA[mt][3]};
                    *(float4*)&outA[(size_t)n_cur * 64 + mt * 16 + quad * 4] = st;
                }
#pragma unroll
                for (int j = 0; j < 3; ++j) {
                    float4 st = {accV[j * 4 + 0], accV[j * 4 + 1], accV[j * 4 + 2], accV[j * 4 + 3]};
                    *(float4*)&outV[(size_t)n_cur * 48 + quad * 12 + j * 4] = st;
                }
            }
#pragma unroll
            for (int mt = 0; mt < 4; ++mt)
#pragma unroll
                for (int r = 0; r < 4; ++r) accA[mt][r] = 0.f;
#pragma unroll
            for (int j = 0; j < 12; ++j) accV[j] = 0.f;
        }

        // ---- shift
        n_cur = n_nxt; j_cur = j_nxt; deg_cur = dnx; hc = hn;
        if (j_cur + 16 < deg_cur) { n_nxt = n_cur; j_nxt = j_cur + 16; }
        else                      { n_nxt = n_cur + NODE_STRIDE; j_nxt = 0; }
    }
}

extern "C" void kernel_launch(void* const* d_in, const int* in_sizes, int n_in,
                              void* d_out, int out_size, void* d_ws, size_t ws_size,
                              hipStream_t stream) {
    const float* r_ij  = (const float*)d_in[0];
    const float* x_a   = (const float*)d_in[1];
    const float* x_v   = (const float*)d_in[2];
    const int*   src   = (const int*)d_in[3];
    const int*   dst   = (const int*)d_in[4];
    const float* W_L0  = (const float*)d_in[5];
    const float* W_L1  = (const float*)d_in[6];
    const float* W_enc = (const float*)d_in[7];
    const float* b_enc = (const float*)d_in[8];
    const float* WY000 = (const float*)d_in[9];
    const float* WY110 = (const float*)d_in[10];
    const float* WY011 = (const float*)d_in[11];
    const float* WY101 = (const float*)d_in[12];
    const float* WY111 = (const float*)d_in[13];
    const float* Wm1   = (const float*)d_in[14];
    const float* bm1   = (const float*)d_in[15];
    const float* Wm2   = (const float*)d_in[16];
    const float* bm2   = (const float*)d_in[17];
    const float* Wm3   = (const float*)d_in[18];
    float* out = (float*)d_out;

    char* ws = (char*)d_ws;
    unsigned short* rec = (unsigned short*)(ws + REC_OFF);
    int* cnt            = (int*)(ws + CNT_OFF);
    int4* ellp          = (int4*)(ws + ELLP_OFF);

    node_kernel<<<(N_NODES * 32) / 256, 256, 0, stream>>>(x_a, x_v, W_L0, W_L1, rec, cnt);
    ell_kernel<<<(N_EDGES + 255) / 256, 256, 0, stream>>>(src, dst, r_ij, cnt, ellp);
    node_major_kernel<<<768, 256, 0, stream>>>(ellp, W_enc, b_enc,
            WY000, WY110, WY011, WY101, WY111, Wm1, bm1, Wm2, bm2, Wm3,
            rec, cnt, out);
}